// Round 8
// baseline (199.269 us; speedup 1.0000x reference)
//
#include <hip/hip_runtime.h>
#include <hip/hip_bf16.h>

// ============================================================================
// ExtraAttention on MI355X (gfx950), bf16 MFMA pipeline.
// R17: attn occupancy fix — cross-round algebra shows attn stuck at ~38.6us
//      with staging-volume changes null (R16); both R13/R16 ran only 2
//      waves/SIMD (grid-limited). Now 2048 blocks x 128 thr (one q-group per
//      block, no pairing), single-buffered K/V (20.9KB LDS) -> 7 blocks/CU
//      ~ 14 waves/CU: other blocks hide each block's barrier/chain stalls.
//      Same-bh blocks stay on one XCD (stride 64 = 0 mod 8).
//      gemm_fused(R14) / prep / proj byte-identical to R16.
// Dims: B=4 S=1024 P=128 NX=1024 H=16 dh=64 T=1152
// ============================================================================

typedef __attribute__((ext_vector_type(8))) short bf16x8;
typedef __attribute__((ext_vector_type(4))) float f32x4;

#define MFMA16(a, b, c) __builtin_amdgcn_mfma_f32_16x16x32_bf16((a), (b), (c), 0, 0, 0)

#define GLOAD_LDS16(g, l)                                                  \
    __builtin_amdgcn_global_load_lds(                                      \
        (const __attribute__((address_space(1))) void*)(const void*)(g),   \
        (__attribute__((address_space(3))) void*)(void*)(l), 16, 0, 0)

static __device__ __forceinline__ unsigned short f2bf(float f) {
    union { float f; unsigned int u; } v; v.f = f;
    unsigned int u = v.u;
    return (unsigned short)((u + 0x7fffu + ((u >> 16) & 1u)) >> 16);  // RNE
}

// ---------------------------------------------------------------------------
// Fused prep: fp32->bf16 converts (x, M) + 3 weight transposes (64x64 tiles)
// + key-bias build.
static __device__ __forceinline__ void transpose64(const float* __restrict__ W,
                                                   unsigned short* __restrict__ Wt,
                                                   int K, int N, int bx, int by,
                                                   float* tile /* [64][65] */) {
    const int n0 = bx * 64, k0 = by * 64;
    const int tr = threadIdx.x >> 2, tc = (threadIdx.x & 3) * 16;
    #pragma unroll
    for (int i = 0; i < 4; i++) {
        float4 v = *(const float4*)&W[(size_t)(k0 + tr) * N + n0 + tc + i * 4];
        tile[tr * 65 + tc + i * 4 + 0] = v.x;
        tile[tr * 65 + tc + i * 4 + 1] = v.y;
        tile[tr * 65 + tc + i * 4 + 2] = v.z;
        tile[tr * 65 + tc + i * 4 + 3] = v.w;
    }
    __syncthreads();
    union { ushort4 u4[2]; unsigned short s[8]; } pk[2];
    #pragma unroll
    for (int half = 0; half < 2; half++)
        #pragma unroll
        for (int i = 0; i < 8; i++)
            pk[half].s[i] = f2bf(tile[(tc + half * 8 + i) * 65 + tr]);
    unsigned short* dst = &Wt[(size_t)(n0 + tr) * K + k0 + tc];
    *(ushort4*)(dst + 0) = pk[0].u4[0];
    *(ushort4*)(dst + 4) = pk[0].u4[1];
    *(ushort4*)(dst + 8) = pk[1].u4[0];
    *(ushort4*)(dst + 12) = pk[1].u4[1];
}

__global__ void prep_all(const float* __restrict__ x, const float* __restrict__ Mem,
                         unsigned short* __restrict__ x_bf, unsigned short* __restrict__ M_bf,
                         const float* __restrict__ W_attn, const float* __restrict__ W_mem,
                         const float* __restrict__ W_proj, unsigned short* __restrict__ Wat,
                         unsigned short* __restrict__ Wmt, unsigned short* __restrict__ Wpt,
                         const float* __restrict__ Mmask, const float* __restrict__ amask,
                         float* __restrict__ biasT) {
    __shared__ float tile[64 * 65];
    int bid = blockIdx.x;
    if (bid < 4608) {
        int i = bid * 256 + threadIdx.x;
        if (i < 1048576) {
            float4 v = ((const float4*)x)[i];
            ushort4 o; o.x = f2bf(v.x); o.y = f2bf(v.y); o.z = f2bf(v.z); o.w = f2bf(v.w);
            ((ushort4*)x_bf)[i] = o;
        } else {
            int j = i - 1048576;
            float4 v = ((const float4*)Mem)[j];
            ushort4 o; o.x = f2bf(v.x); o.y = f2bf(v.y); o.z = f2bf(v.z); o.w = f2bf(v.w);
            ((ushort4*)M_bf)[j] = o;
        }
        return;
    }
    bid -= 4608;
    if (bid < 768) {
        transpose64(W_attn, Wat, 1024, 3072, bid % 48, bid / 48, tile);
    } else if (bid < 1280) {
        int t = bid - 768;  transpose64(W_mem, Wmt, 1024, 2048, t % 32, t / 32, tile);
    } else if (bid < 1536) {
        int t = bid - 1280; transpose64(W_proj, Wpt, 1024, 1024, t % 16, t / 16, tile);
    } else {
        int i = (bid - 1536) * 256 + threadIdx.x;
        if (i < 4 * 1152) {
            int b = i / 1152, t = i % 1152;
            float v = (t < 128) ? (Mmask[b * 128 + t] - 1.f) * 10000.f
                                : amask[b * 1024 + t - 128];
            biasT[i] = v * 1.4426950408889634f;
        }
    }
}

// ---------------------------------------------------------------------------
// R14 gemm_fused: 256x256 tile, BK=64, 512 thr (8 waves 2Mx4N), 128KB dbuf
// XOR-swizzled LDS, 4-phase/K-tile schedule.
// bid<192: QKV (A=x_bf[4096][1024], Bt=Wat[3072][1024], 16x12 tiles, XCD remap)
// else   : EKV (A=M_bf[512][1024],  Bt=Wmt[2048][1024], 2x8 tiles)
__global__ __launch_bounds__(512, 2) void gemm_fused(
        const unsigned short* __restrict__ x_bf, const unsigned short* __restrict__ Wat,
        const float* __restrict__ b_attn, const unsigned short* __restrict__ M_bf,
        const unsigned short* __restrict__ Wmt, const float* __restrict__ b_mem,
        unsigned short* __restrict__ Qbuf, unsigned short* __restrict__ Kc,
        unsigned short* __restrict__ Vt) {
    __shared__ unsigned short lds[2][32768];  // [slot][A 16K elems | B 16K elems]
    const int tid = threadIdx.x;
    const int lane = tid & 63, wave = tid >> 6;
    const int quad = lane >> 4, l16 = lane & 15;
    const int l7 = l16 & 7;
    const int srow = lane >> 3;                 // staging: row within 8-row chunk
    const int sblk = (lane & 7) ^ srow;         // staging: pre-swizzled src block
    const int wrow = wave * 16;                 // staging: wave's rows in a half
    const int wm = (wave & 1) * 128;            // wave output rows (M)
    const int wn = (wave >> 1) * 64;            // wave output cols (N)

    int tm, tn;
    const unsigned short *Ab, *Bb;
    const float* bias;
    bool qkv;
    if (blockIdx.x < 192) {
        const int nb = (blockIdx.x & 7) * 24 + (blockIdx.x >> 3);  // XCD-contig
        tm = nb & 15; tn = nb >> 4;            // 16 x 12
        Ab = x_bf; Bb = Wat; bias = b_attn; qkv = true;
    } else {
        const int e = blockIdx.x - 192;
        tm = e >> 3; tn = e & 7;               // 2 x 8
        Ab = M_bf; Bb = Wmt; bias = b_mem; qkv = false;
    }
    const int Mrow0 = tm * 256, Nrow0 = tn * 256;

    // stage one 128-row half (2 x gload_lds per thread) of K-tile kt1 into slot
#define STG(slot, dstoff, srcp, row0, kt1)                                     \
    { _Pragma("unroll")                                                        \
      for (int c = 0; c < 2; c++)                                              \
          GLOAD_LDS16((srcp) + (size_t)((row0) + wrow + c * 8 + srow) * 1024 + \
                          (kt1) * 64 + sblk * 8,                               \
                      &lds[slot][(dstoff) + (wrow + c * 8) * 64]); }

    // prologue: stage K-tile 0 fully into slot 0
    STG(0, 16384, Bb, Nrow0, 0); STG(0, 24576, Bb, Nrow0 + 128, 0);
    STG(0, 0,     Ab, Mrow0, 0); STG(0, 8192,  Ab, Mrow0 + 128, 0);
    asm volatile("s_waitcnt vmcnt(0)\n\ts_barrier" ::: "memory");

    f32x4 acc[8][4] = {};
    for (int kt = 0; kt < 16; kt++) {
        const int s = kt & 1, nx = s ^ 1;
        bf16x8 bfr[4][2];
        #pragma unroll
        for (int p = 0; p < 4; p++) {
            bf16x8 af[2][2];
            #pragma unroll
            for (int k = 0; k < 2; k++)
                #pragma unroll
                for (int ks = 0; ks < 2; ks++)
                    af[k][ks] = *(const bf16x8*)&lds[s][(wm + (2 * p + k) * 16 + l16) * 64 +
                                                       (((ks * 4 + quad) ^ l7) * 8)];
            if (p == 0) {
                #pragma unroll
                for (int j = 0; j < 4; j++)
                    #pragma unroll
                    for (int ks = 0; ks < 2; ks++)
                        bfr[j][ks] = *(const bf16x8*)&lds[s][16384 + (wn + j * 16 + l16) * 64 +
                                                            (((ks * 4 + quad) ^ l7) * 8)];
            }
            if (kt < 15) {  // stage kt+1 into slot nx (fully freed last K-tile)
                if (p == 0) { STG(nx, 16384, Bb, Nrow0, kt + 1);
                              STG(nx, 24576, Bb, Nrow0 + 128, kt + 1); }
                else if (p == 1) { STG(nx, 0,    Ab, Mrow0, kt + 1); }
                else if (p == 2) { STG(nx, 8192, Ab, Mrow0 + 128, kt + 1); }
            }
            if (p == 3) asm volatile("s_waitcnt vmcnt(0)\n\ts_barrier" ::: "memory");
            else        asm volatile("s_barrier" ::: "memory");
            __builtin_amdgcn_s_setprio(1);
            #pragma unroll
            for (int k = 0; k < 2; k++)
                #pragma unroll
                for (int j = 0; j < 4; j++) {
                    acc[2 * p + k][j] = MFMA16(af[k][0], bfr[j][0], acc[2 * p + k][j]);
                    acc[2 * p + k][j] = MFMA16(af[k][1], bfr[j][1], acc[2 * p + k][j]);
                }
            __builtin_amdgcn_s_setprio(0);
            asm volatile("s_barrier" ::: "memory");
        }
    }
#undef STG
    __syncthreads();  // main loop fully done; LDS reusable for transposes

    float bj[4];
    #pragma unroll
    for (int j = 0; j < 4; j++) bj[j] = bias[Nrow0 + wn + j * 16 + l16];

    if (qkv) {
        const int b = tm >> 2;
        const int sb = (tm & 3) * 256 + wm;    // row within [0,1024)
        if (tn < 4) {
            // ---- q -> Qbuf[4096][1024]
            #pragma unroll
            for (int i = 0; i < 8; i++) {
                const int row = Mrow0 + wm + i * 16 + quad * 4;
                #pragma unroll
                for (int j = 0; j < 4; j++) {
                    const int col = Nrow0 + wn + j * 16 + l16;
                    #pragma unroll
                    for (int r = 0; r < 4; r++)
                        Qbuf[(size_t)(row + r) * 1024 + col] = f2bf(acc[i][j][r] + bj[j]);
                }
            }
        } else if (tn < 8) {
            // ---- k -> Kc[bh][t=s+128][d]
            const int cb = (tn - 4) * 256 + wn;
            unsigned short* kb2 = Kc + (size_t)((b << 4) | (cb >> 6)) * 73728;
            #pragma unroll
            for (int i = 0; i < 8; i++) {
                const int s0 = sb + i * 16 + quad * 4;
                #pragma unroll
                for (int j = 0; j < 4; j++) {
                    const int d = j * 16 + l16;
                    #pragma unroll
                    for (int r = 0; r < 4; r++)
                        kb2[(size_t)(128 + s0 + r) * 64 + d] = f2bf(acc[i][j][r] + bj[j]);
                }
            }
        } else {
            // ---- v -> Vt[bh][d][t] via per-wave LDS transpose (64x64, stride 68)
            const int vb = (tn - 8) * 256 + wn;
            unsigned short* Tw = &lds[0][0] + wave * 4352;
            unsigned short* vdb = Vt + (size_t)((b << 4) | (vb >> 6)) * 73728;
            #pragma unroll
            for (int hf = 0; hf < 2; hf++) {
                #pragma unroll
                for (int i2 = 0; i2 < 4; i2++)
                    #pragma unroll
                    for (int j = 0; j < 4; j++)
                        #pragma unroll
                        for (int r = 0; r < 4; r++)
                            Tw[(j * 16 + l16) * 68 + i2 * 16 + quad * 4 + r] =
                                f2bf(acc[hf * 4 + i2][j][r] + bj[j]);
                unsigned short* vd = vdb + (size_t)lane * 1152 + 128 + sb + hf * 64;
                #pragma unroll
                for (int ch = 0; ch < 8; ch++)
                    *(bf16x8*)(vd + ch * 8) = *(const bf16x8*)&Tw[lane * 68 + ch * 8];
            }
        }
    } else {
        const int b = (Mrow0 + wm) >> 7;
        if (tn < 4) {
            // ---- ek -> Kc[bh][t=p][d]
            const int cb = tn * 256 + wn;
            unsigned short* kb2 = Kc + (size_t)((b << 4) | (cb >> 6)) * 73728;
            #pragma unroll
            for (int i = 0; i < 8; i++) {
                const int p0 = i * 16 + quad * 4;
                #pragma unroll
                for (int j = 0; j < 4; j++) {
                    const int d = j * 16 + l16;
                    #pragma unroll
                    for (int r = 0; r < 4; r++)
                        kb2[(size_t)(p0 + r) * 64 + d] = f2bf(acc[i][j][r] + bj[j]);
                }
            }
        } else {
            // ---- ev -> Vt[bh][d][p] via per-wave LDS transpose
            const int vb = (tn - 4) * 256 + wn;
            unsigned short* Tw = &lds[0][0] + wave * 4352;
            unsigned short* vdb = Vt + (size_t)((b << 4) | (vb >> 6)) * 73728;
            #pragma unroll
            for (int hf = 0; hf < 2; hf++) {
                #pragma unroll
                for (int i2 = 0; i2 < 4; i2++)
                    #pragma unroll
                    for (int j = 0; j < 4; j++)
                        #pragma unroll
                        for (int r = 0; r < 4; r++)
                            Tw[(j * 16 + l16) * 68 + i2 * 16 + quad * 4 + r] =
                                f2bf(acc[hf * 4 + i2][j][r] + bj[j]);
                unsigned short* vd = vdb + (size_t)lane * 1152 + hf * 64;
                #pragma unroll
                for (int ch = 0; ch < 8; ch++)
                    *(bf16x8*)(vd + ch * 8) = *(const bf16x8*)&Tw[lane * 68 + ch * 8];
            }
        }
    }
}

// ---------------------------------------------------------------------------
// Attention (R17): 2048 blocks x 128 thr — ONE q-group (32 rows) per block,
// no pairing. Single-buffered K/V (20.9KB LDS -> 7 blocks/CU ~ 14 waves/CU):
// TLP from co-resident blocks hides the per-tile serial chain + drains.
// bh = blk&63 (same-bh blocks on one XCD: stride 64 = 0 mod 8), qg = blk>>6.
__global__ __launch_bounds__(128) void attn_kernel(const unsigned short* __restrict__ Qbuf,
                                                   const unsigned short* __restrict__ Kc,
                                                   const unsigned short* __restrict__ Vt,
                                                   const float* __restrict__ biasT,
                                                   unsigned short* __restrict__ Aout) {
    __shared__ unsigned short Ks[64 * 64];     // swizzled [t][64 k-elems]
    __shared__ unsigned short Vs[64 * 64];     // swizzled [d][64 t-elems]
    __shared__ unsigned short Ps[2][16 * 72];  // per-wave P tile [s][t]
    const int tid = threadIdx.x;
    const int lane = tid & 63, wave = tid >> 6;
    const int quad = lane >> 4, l16 = lane & 15;
    const int blk = blockIdx.x;                 // 2048 = 64 bh x 32 qg
    const int bh = blk & 63;
    const int qg = blk >> 6;                    // 0..31
    const int h = bh & 15, b = bh >> 4;

    const unsigned short* Kb = Kc + (size_t)bh * 73728;
    const unsigned short* Vb = Vt + (size_t)bh * 73728;
    const float* bias_b = biasT + b * 1152;

    const int srow = lane >> 3;                        // row within 8-row chunk
    const int scol = ((lane & 7) ^ srow) * 8;          // swizzled 16B block
    const int rswz = l16 & 7;                          // read-side swizzle key
    const int w32 = wave * 32;                         // this wave's staging rows

    bf16x8 ones;
    #pragma unroll
    for (int j = 0; j < 8; j++) ones[j] = (short)0x3F80;  // bf16 1.0

    const int qrow0 = qg * 32;
    const int qrow_w = qrow0 + wave * 16;

    bf16x8 qf[2];
    #pragma unroll
    for (int k2 = 0; k2 < 2; k2++)
        qf[k2] = *(const bf16x8*)(Qbuf + (size_t)(b * 1024 + qrow_w + l16) * 1024 +
                                  h * 64 + k2 * 32 + quad * 8);

    f32x4 o[4] = {};
    f32x4 oden = {};
    const int tmax = min(1152, ((qrow0 + 223) >> 6) << 6);
    const int sg = qrow_w + l16;

    for (int t0 = 0; t0 < tmax; t0 += 64) {
        __syncthreads();  // all waves done reading previous tile
        {   // wave-uniform staging: wave w stages rows w*32..w*32+31 of K and V
            const unsigned short* gk = Kb + (size_t)(t0 + w32 + srow) * 64 + scol;
            const unsigned short* gv = Vb + (size_t)(w32 + srow) * 1152 + t0 + scol;
            #pragma unroll
            for (int cc = 0; cc < 4; cc++) {
                GLOAD_LDS16(gk + (size_t)(cc * 8) * 64,   &Ks[(w32 + cc * 8) * 64]);
                GLOAD_LDS16(gv + (size_t)(cc * 8) * 1152, &Vs[(w32 + cc * 8) * 64]);
            }
        }
        __syncthreads();  // drains vmcnt -> staged tile visible
        if (t0 <= qrow_w + 143) {
            const bool nomask = (t0 + 63 <= 128 + qrow_w);
            float4 bt[4];
            #pragma unroll
            for (int tn = 0; tn < 4; tn++)
                bt[tn] = *(const float4*)(bias_b + t0 + tn * 16 + quad * 4);
            #pragma unroll
            for (int tn = 0; tn < 4; tn++) {
                bf16x8 kf0 = *(const bf16x8*)&Ks[(tn * 16 + l16) * 64 + (quad ^ rswz) * 8];
                bf16x8 kf1 = *(const bf16x8*)&Ks[(tn * 16 + l16) * 64 + ((quad + 4) ^ rswz) * 8];
                f32x4 st = {};
                st = MFMA16(kf0, qf[0], st);
                st = MFMA16(kf1, qf[1], st);
                float p[4];
                #pragma unroll
                for (int r = 0; r < 4; r++) {
                    float e = __builtin_amdgcn_exp2f(st[r] * 0.18033688011112042f + bt[tn][r]);
                    if (!nomask) {
                        const int tg = t0 + tn * 16 + quad * 4 + r;
                        e = (tg < 128 || tg - 128 <= sg) ? e : 0.f;
                    }
                    p[r] = e;
                }
                union { ushort4 u; __hip_bfloat162 h2[2]; } pk;
                pk.h2[0] = __float22bfloat162_rn(float2{p[0], p[1]});
                pk.h2[1] = __float22bfloat162_rn(float2{p[2], p[3]});
                *(ushort4*)&Ps[wave][l16 * 72 + tn * 16 + quad * 4] = pk.u;
            }
            #pragma unroll
            for (int tk = 0; tk < 2; tk++) {
                bf16x8 pf = *(const bf16x8*)&Ps[wave][l16 * 72 + tk * 32 + quad * 8];
                oden = MFMA16(pf, ones, oden);
                #pragma unroll
                for (int dn = 0; dn < 4; dn++) {
                    bf16x8 vf = *(const bf16x8*)&Vs[(dn * 16 + l16) * 64 +
                                                    ((tk * 4 + quad) ^ rswz) * 8];
                    o[dn] = MFMA16(pf, vf, o[dn]);
                }
            }
        }
    }

    // epilogue: o C-layout row s = quad*4+r, col d = dn*16+l16
    #pragma unroll
    for (int r = 0; r < 4; r++) {
        const float inv = 1.f / oden[r];
        const size_t orow = (size_t)(b * 1024 + qrow_w + quad * 4 + r) * 1024 + h * 64;
        #pragma unroll
        for (int dn = 0; dn < 4; dn++)
            Aout[orow + dn * 16 + l16] = f2bf(o[dn][r] * inv);
    }
}

// ---------------------------------------------------------------------------
// proj (R7): 128x64 tiles, 512 blocks, BK=32 m97 staging, fp32 out.
__global__ __launch_bounds__(256) void gemm_proj(const unsigned short* __restrict__ Abuf,
                                                 const unsigned short* __restrict__ Wpt,
                                                 const float* __restrict__ b_proj,
                                                 float* __restrict__ out) {
    __shared__ unsigned short As[128 * 32];
    __shared__ unsigned short Bs[64 * 32];
    const int tid = threadIdx.x;
    const int lane = tid & 63, wave = tid >> 6;
    const int quad = lane >> 4, l16 = lane & 15;
    const int wm = (wave & 1) * 64, wn = (wave >> 1) * 32;
    const int bm = blockIdx.x & 31, bn = blockIdx.x >> 5;
    const int crow = lane >> 2, ccol = (lane & 3) * 8;
    const unsigned short* Abase = Abuf + (size_t)(bm * 128 + crow) * 1024 + ccol;
    const unsigned short* Bbase = Wpt + (size_t)(bn * 64 + crow) * 1024 + ccol;

    f32x4 acc[4][2] = {};
    for (int k0 = 0; k0 < 1024; k0 += 32) {
        __syncthreads();
        #pragma unroll
        for (int cc = 0; cc < 3; cc++) {
            const int c = wave * 3 + cc;
            if (c < 8) GLOAD_LDS16(Abase + (size_t)(c * 16) * 1024 + k0, &As[c * 512]);
            else if (c < 12) GLOAD_LDS16(Bbase + (size_t)((c - 8) * 16) * 1024 + k0, &Bs[(c - 8) * 512]);
        }
        __syncthreads();
        bf16x8 af[4], bf[2];
        #pragma unroll
        for (int i = 0; i < 4; i++) af[i] = *(const bf16x8*)&As[(wm + i * 16 + l16) * 32 + quad * 8];
        #pragma unroll
        for (int j = 0; j < 2; j++) bf[j] = *(const bf16x8*)&Bs[(wn + j * 16 + l16) * 32 + quad * 8];
        #pragma unroll
        for (int i = 0; i < 4; i++)
            #pragma unroll
            for (int j = 0; j < 2; j++)
                acc[i][j] = MFMA16(af[i], bf[j], acc[i][j]);
    }
    float bj[2];
    #pragma unroll
    for (int j = 0; j < 2; j++) bj[j] = b_proj[bn * 64 + wn + j * 16 + l16];
    #pragma unroll
    for (int i = 0; i < 4; i++) {
        const int row = bm * 128 + wm + i * 16 + quad * 4;
        #pragma unroll
        for (int j = 0; j < 2; j++) {
            const int col = bn * 64 + wn + j * 16 + l16;
            #pragma unroll
            for (int r = 0; r < 4; r++)
                out[(size_t)(row + r) * 1024 + col] = acc[i][j][r] + bj[j];
        }
    }
}

// ---------------------------------------------------------------------------
extern "C" void kernel_launch(void* const* d_in, const int* in_sizes, int n_in,
                              void* d_out, int out_size, void* d_ws, size_t ws_size,
                              hipStream_t stream) {
    const float* x      = (const float*)d_in[0];
    const float* Mem    = (const float*)d_in[1];
    const float* Mmask  = (const float*)d_in[2];
    const float* amask  = (const float*)d_in[3];
    const float* W_attn = (const float*)d_in[4];
    const float* b_attn = (const float*)d_in[5];
    const float* W_mem  = (const float*)d_in[6];
    const float* b_mem  = (const float*)d_in[7];
    const float* W_proj = (const float*)d_in[8];
    const float* b_proj = (const float*)d_in[9];
    float* out = (float*)d_out;

    char* ws = (char*)d_ws;
    unsigned short* x_bf  = (unsigned short*)ws;  ws += (size_t)4096 * 1024 * 2;
    unsigned short* M_bf  = (unsigned short*)ws;  ws += (size_t)512 * 1024 * 2;
    unsigned short* Wat   = (unsigned short*)ws;  ws += (size_t)3072 * 1024 * 2;
    unsigned short* Wmt   = (unsigned short*)ws;  ws += (size_t)2048 * 1024 * 2;
    unsigned short* Wpt   = (unsigned short*)ws;  ws += (size_t)1024 * 1024 * 2;
    unsigned short* Qbuf  = (unsigned short*)ws;  ws += (size_t)4096 * 1024 * 2;
    unsigned short* Abuf  = (unsigned short*)ws;  ws += (size_t)4096 * 1024 * 2;
    unsigned short* Kc    = (unsigned short*)ws;  ws += (size_t)64 * 1152 * 64 * 2;
    unsigned short* Vt    = (unsigned short*)ws;  ws += (size_t)64 * 64 * 1152 * 2;
    float*          biasT = (float*)ws;           ws += (size_t)4 * 1152 * 4;

    prep_all<<<6163, 256, 0, stream>>>(x, Mem, x_bf, M_bf, W_attn, W_mem, W_proj,
                                       Wat, Wmt, Wpt, Mmask, amask, biasT);
    gemm_fused<<<208, 512, 0, stream>>>(x_bf, Wat, b_attn, M_bf, Wmt, b_mem,
                                        Qbuf, Kc, Vt);
    attn_kernel<<<2048, 128, 0, stream>>>(Qbuf, Kc, Vt, biasT, Abuf);
    gemm_proj<<<512, 256, 0, stream>>>(Abuf, Wpt, b_proj, out);
}

// Round 9
// 196.929 us; speedup vs baseline: 1.0119x; 1.0119x over previous
//
#include <hip/hip_runtime.h>
#include <hip/hip_bf16.h>

// ============================================================================
// ExtraAttention on MI355X (gfx950), bf16 MFMA pipeline.
// R18: gemm_fused = R14 schedule with ALL 8 of kt+1's gload_lds issued at
//      p0 (was B@p0/A-lo@p1/A-hi@p2): every load now has 3 phases (~750cy)
//      of MFMA cover before the p3 vmcnt(0) drain, vs 1 phase for the
//      p2-issued loads in R14 (the modeled per-kt stall). Fine interleave
//      kept (m196: coarse split hurts). attn = R16 (QBLK=64, best total).
//      prep / proj unchanged.
// Dims: B=4 S=1024 P=128 NX=1024 H=16 dh=64 T=1152
// ============================================================================

typedef __attribute__((ext_vector_type(8))) short bf16x8;
typedef __attribute__((ext_vector_type(4))) float f32x4;

#define MFMA16(a, b, c) __builtin_amdgcn_mfma_f32_16x16x32_bf16((a), (b), (c), 0, 0, 0)

#define GLOAD_LDS16(g, l)                                                  \
    __builtin_amdgcn_global_load_lds(                                      \
        (const __attribute__((address_space(1))) void*)(const void*)(g),   \
        (__attribute__((address_space(3))) void*)(void*)(l), 16, 0, 0)

static __device__ __forceinline__ unsigned short f2bf(float f) {
    union { float f; unsigned int u; } v; v.f = f;
    unsigned int u = v.u;
    return (unsigned short)((u + 0x7fffu + ((u >> 16) & 1u)) >> 16);  // RNE
}

// ---------------------------------------------------------------------------
// Fused prep: fp32->bf16 converts (x, M) + 3 weight transposes (64x64 tiles)
// + key-bias build.
static __device__ __forceinline__ void transpose64(const float* __restrict__ W,
                                                   unsigned short* __restrict__ Wt,
                                                   int K, int N, int bx, int by,
                                                   float* tile /* [64][65] */) {
    const int n0 = bx * 64, k0 = by * 64;
    const int tr = threadIdx.x >> 2, tc = (threadIdx.x & 3) * 16;
    #pragma unroll
    for (int i = 0; i < 4; i++) {
        float4 v = *(const float4*)&W[(size_t)(k0 + tr) * N + n0 + tc + i * 4];
        tile[tr * 65 + tc + i * 4 + 0] = v.x;
        tile[tr * 65 + tc + i * 4 + 1] = v.y;
        tile[tr * 65 + tc + i * 4 + 2] = v.z;
        tile[tr * 65 + tc + i * 4 + 3] = v.w;
    }
    __syncthreads();
    union { ushort4 u4[2]; unsigned short s[8]; } pk[2];
    #pragma unroll
    for (int half = 0; half < 2; half++)
        #pragma unroll
        for (int i = 0; i < 8; i++)
            pk[half].s[i] = f2bf(tile[(tc + half * 8 + i) * 65 + tr]);
    unsigned short* dst = &Wt[(size_t)(n0 + tr) * K + k0 + tc];
    *(ushort4*)(dst + 0) = pk[0].u4[0];
    *(ushort4*)(dst + 4) = pk[0].u4[1];
    *(ushort4*)(dst + 8) = pk[1].u4[0];
    *(ushort4*)(dst + 12) = pk[1].u4[1];
}

__global__ void prep_all(const float* __restrict__ x, const float* __restrict__ Mem,
                         unsigned short* __restrict__ x_bf, unsigned short* __restrict__ M_bf,
                         const float* __restrict__ W_attn, const float* __restrict__ W_mem,
                         const float* __restrict__ W_proj, unsigned short* __restrict__ Wat,
                         unsigned short* __restrict__ Wmt, unsigned short* __restrict__ Wpt,
                         const float* __restrict__ Mmask, const float* __restrict__ amask,
                         float* __restrict__ biasT) {
    __shared__ float tile[64 * 65];
    int bid = blockIdx.x;
    if (bid < 4608) {
        int i = bid * 256 + threadIdx.x;
        if (i < 1048576) {
            float4 v = ((const float4*)x)[i];
            ushort4 o; o.x = f2bf(v.x); o.y = f2bf(v.y); o.z = f2bf(v.z); o.w = f2bf(v.w);
            ((ushort4*)x_bf)[i] = o;
        } else {
            int j = i - 1048576;
            float4 v = ((const float4*)Mem)[j];
            ushort4 o; o.x = f2bf(v.x); o.y = f2bf(v.y); o.z = f2bf(v.z); o.w = f2bf(v.w);
            ((ushort4*)M_bf)[j] = o;
        }
        return;
    }
    bid -= 4608;
    if (bid < 768) {
        transpose64(W_attn, Wat, 1024, 3072, bid % 48, bid / 48, tile);
    } else if (bid < 1280) {
        int t = bid - 768;  transpose64(W_mem, Wmt, 1024, 2048, t % 32, t / 32, tile);
    } else if (bid < 1536) {
        int t = bid - 1280; transpose64(W_proj, Wpt, 1024, 1024, t % 16, t / 16, tile);
    } else {
        int i = (bid - 1536) * 256 + threadIdx.x;
        if (i < 4 * 1152) {
            int b = i / 1152, t = i % 1152;
            float v = (t < 128) ? (Mmask[b * 128 + t] - 1.f) * 10000.f
                                : amask[b * 1024 + t - 128];
            biasT[i] = v * 1.4426950408889634f;
        }
    }
}

// ---------------------------------------------------------------------------
// R18 gemm_fused: 256x256 tile, BK=64, 512 thr (8 waves 2Mx4N), 128KB dbuf
// XOR-swizzled LDS, 4-phase/K-tile schedule; kt+1 staged ENTIRELY at p0.
// bid<192: QKV (A=x_bf[4096][1024], Bt=Wat[3072][1024], 16x12 tiles, XCD remap)
// else   : EKV (A=M_bf[512][1024],  Bt=Wmt[2048][1024], 2x8 tiles)
__global__ __launch_bounds__(512, 2) void gemm_fused(
        const unsigned short* __restrict__ x_bf, const unsigned short* __restrict__ Wat,
        const float* __restrict__ b_attn, const unsigned short* __restrict__ M_bf,
        const unsigned short* __restrict__ Wmt, const float* __restrict__ b_mem,
        unsigned short* __restrict__ Qbuf, unsigned short* __restrict__ Kc,
        unsigned short* __restrict__ Vt) {
    __shared__ unsigned short lds[2][32768];  // [slot][A 16K elems | B 16K elems]
    const int tid = threadIdx.x;
    const int lane = tid & 63, wave = tid >> 6;
    const int quad = lane >> 4, l16 = lane & 15;
    const int l7 = l16 & 7;
    const int srow = lane >> 3;                 // staging: row within 8-row chunk
    const int sblk = (lane & 7) ^ srow;         // staging: pre-swizzled src block
    const int wrow = wave * 16;                 // staging: wave's rows in a half
    const int wm = (wave & 1) * 128;            // wave output rows (M)
    const int wn = (wave >> 1) * 64;            // wave output cols (N)

    int tm, tn;
    const unsigned short *Ab, *Bb;
    const float* bias;
    bool qkv;
    if (blockIdx.x < 192) {
        const int nb = (blockIdx.x & 7) * 24 + (blockIdx.x >> 3);  // XCD-contig
        tm = nb & 15; tn = nb >> 4;            // 16 x 12
        Ab = x_bf; Bb = Wat; bias = b_attn; qkv = true;
    } else {
        const int e = blockIdx.x - 192;
        tm = e >> 3; tn = e & 7;               // 2 x 8
        Ab = M_bf; Bb = Wmt; bias = b_mem; qkv = false;
    }
    const int Mrow0 = tm * 256, Nrow0 = tn * 256;

    // stage one 128-row half (2 x gload_lds per thread) of K-tile kt1 into slot
#define STG(slot, dstoff, srcp, row0, kt1)                                     \
    { _Pragma("unroll")                                                        \
      for (int c = 0; c < 2; c++)                                              \
          GLOAD_LDS16((srcp) + (size_t)((row0) + wrow + c * 8 + srow) * 1024 + \
                          (kt1) * 64 + sblk * 8,                               \
                      &lds[slot][(dstoff) + (wrow + c * 8) * 64]); }

    // prologue: stage K-tile 0 fully into slot 0
    STG(0, 16384, Bb, Nrow0, 0); STG(0, 24576, Bb, Nrow0 + 128, 0);
    STG(0, 0,     Ab, Mrow0, 0); STG(0, 8192,  Ab, Mrow0 + 128, 0);
    asm volatile("s_waitcnt vmcnt(0)\n\ts_barrier" ::: "memory");

    f32x4 acc[8][4] = {};
    for (int kt = 0; kt < 16; kt++) {
        const int s = kt & 1, nx = s ^ 1;
        bf16x8 bfr[4][2];
        #pragma unroll
        for (int p = 0; p < 4; p++) {
            bf16x8 af[2][2];
            #pragma unroll
            for (int k = 0; k < 2; k++)
                #pragma unroll
                for (int ks = 0; ks < 2; ks++)
                    af[k][ks] = *(const bf16x8*)&lds[s][(wm + (2 * p + k) * 16 + l16) * 64 +
                                                       (((ks * 4 + quad) ^ l7) * 8)];
            if (p == 0) {
                #pragma unroll
                for (int j = 0; j < 4; j++)
                    #pragma unroll
                    for (int ks = 0; ks < 2; ks++)
                        bfr[j][ks] = *(const bf16x8*)&lds[s][16384 + (wn + j * 16 + l16) * 64 +
                                                            (((ks * 4 + quad) ^ l7) * 8)];
                if (kt < 15) {  // ALL of kt+1 staged here: 3 phases of cover
                    STG(nx, 16384, Bb, Nrow0, kt + 1);
                    STG(nx, 24576, Bb, Nrow0 + 128, kt + 1);
                    STG(nx, 0,     Ab, Mrow0, kt + 1);
                    STG(nx, 8192,  Ab, Mrow0 + 128, kt + 1);
                }
            }
            if (p == 3) asm volatile("s_waitcnt vmcnt(0)\n\ts_barrier" ::: "memory");
            else        asm volatile("s_barrier" ::: "memory");
            __builtin_amdgcn_s_setprio(1);
            #pragma unroll
            for (int k = 0; k < 2; k++)
                #pragma unroll
                for (int j = 0; j < 4; j++) {
                    acc[2 * p + k][j] = MFMA16(af[k][0], bfr[j][0], acc[2 * p + k][j]);
                    acc[2 * p + k][j] = MFMA16(af[k][1], bfr[j][1], acc[2 * p + k][j]);
                }
            __builtin_amdgcn_s_setprio(0);
            asm volatile("s_barrier" ::: "memory");
        }
    }
#undef STG
    __syncthreads();  // main loop fully done; LDS reusable for transposes

    float bj[4];
    #pragma unroll
    for (int j = 0; j < 4; j++) bj[j] = bias[Nrow0 + wn + j * 16 + l16];

    if (qkv) {
        const int b = tm >> 2;
        const int sb = (tm & 3) * 256 + wm;    // row within [0,1024)
        if (tn < 4) {
            // ---- q -> Qbuf[4096][1024]
            #pragma unroll
            for (int i = 0; i < 8; i++) {
                const int row = Mrow0 + wm + i * 16 + quad * 4;
                #pragma unroll
                for (int j = 0; j < 4; j++) {
                    const int col = Nrow0 + wn + j * 16 + l16;
                    #pragma unroll
                    for (int r = 0; r < 4; r++)
                        Qbuf[(size_t)(row + r) * 1024 + col] = f2bf(acc[i][j][r] + bj[j]);
                }
            }
        } else if (tn < 8) {
            // ---- k -> Kc[bh][t=s+128][d]
            const int cb = (tn - 4) * 256 + wn;
            unsigned short* kb2 = Kc + (size_t)((b << 4) | (cb >> 6)) * 73728;
            #pragma unroll
            for (int i = 0; i < 8; i++) {
                const int s0 = sb + i * 16 + quad * 4;
                #pragma unroll
                for (int j = 0; j < 4; j++) {
                    const int d = j * 16 + l16;
                    #pragma unroll
                    for (int r = 0; r < 4; r++)
                        kb2[(size_t)(128 + s0 + r) * 64 + d] = f2bf(acc[i][j][r] + bj[j]);
                }
            }
        } else {
            // ---- v -> Vt[bh][d][t] via per-wave LDS transpose (64x64, stride 68)
            const int vb = (tn - 8) * 256 + wn;
            unsigned short* Tw = &lds[0][0] + wave * 4352;
            unsigned short* vdb = Vt + (size_t)((b << 4) | (vb >> 6)) * 73728;
            #pragma unroll
            for (int hf = 0; hf < 2; hf++) {
                #pragma unroll
                for (int i2 = 0; i2 < 4; i2++)
                    #pragma unroll
                    for (int j = 0; j < 4; j++)
                        #pragma unroll
                        for (int r = 0; r < 4; r++)
                            Tw[(j * 16 + l16) * 68 + i2 * 16 + quad * 4 + r] =
                                f2bf(acc[hf * 4 + i2][j][r] + bj[j]);
                unsigned short* vd = vdb + (size_t)lane * 1152 + 128 + sb + hf * 64;
                #pragma unroll
                for (int ch = 0; ch < 8; ch++)
                    *(bf16x8*)(vd + ch * 8) = *(const bf16x8*)&Tw[lane * 68 + ch * 8];
            }
        }
    } else {
        const int b = (Mrow0 + wm) >> 7;
        if (tn < 4) {
            // ---- ek -> Kc[bh][t=p][d]
            const int cb = tn * 256 + wn;
            unsigned short* kb2 = Kc + (size_t)((b << 4) | (cb >> 6)) * 73728;
            #pragma unroll
            for (int i = 0; i < 8; i++) {
                const int p0 = i * 16 + quad * 4;
                #pragma unroll
                for (int j = 0; j < 4; j++) {
                    const int d = j * 16 + l16;
                    #pragma unroll
                    for (int r = 0; r < 4; r++)
                        kb2[(size_t)(p0 + r) * 64 + d] = f2bf(acc[i][j][r] + bj[j]);
                }
            }
        } else {
            // ---- ev -> Vt[bh][d][p] via per-wave LDS transpose
            const int vb = (tn - 4) * 256 + wn;
            unsigned short* Tw = &lds[0][0] + wave * 4352;
            unsigned short* vdb = Vt + (size_t)((b << 4) | (vb >> 6)) * 73728;
            #pragma unroll
            for (int hf = 0; hf < 2; hf++) {
                #pragma unroll
                for (int i2 = 0; i2 < 4; i2++)
                    #pragma unroll
                    for (int j = 0; j < 4; j++)
                        #pragma unroll
                        for (int r = 0; r < 4; r++)
                            Tw[(j * 16 + l16) * 68 + i2 * 16 + quad * 4 + r] =
                                f2bf(acc[hf * 4 + i2][j][r] + bj[j]);
                unsigned short* vd = vdb + (size_t)lane * 1152 + hf * 64;
                #pragma unroll
                for (int ch = 0; ch < 8; ch++)
                    *(bf16x8*)(vd + ch * 8) = *(const bf16x8*)&Tw[lane * 68 + ch * 8];
            }
        }
    }
}

// ---------------------------------------------------------------------------
// Attention (R16, best-total config): QBLK=64 — 512 blocks x 256 thr
// (4 waves), dbuf K/V, counted vmcnt(4), uniform pairing (21 iters/block).
__global__ __launch_bounds__(256) void attn_kernel(const unsigned short* __restrict__ Qbuf,
                                                   const unsigned short* __restrict__ Kc,
                                                   const unsigned short* __restrict__ Vt,
                                                   const float* __restrict__ biasT,
                                                   unsigned short* __restrict__ Aout) {
    __shared__ unsigned short Ks[2][64 * 64];
    __shared__ unsigned short Vs[2][64 * 64];
    __shared__ unsigned short Ps[4][16 * 72];
    const int tid = threadIdx.x;
    const int lane = tid & 63, wave = tid >> 6;   // wave 0..3
    const int quad = lane >> 4, l16 = lane & 15;
    const int blk = blockIdx.x;                   // 512 = 8 xcd x 8 bh x 8 pair
    const int xcd = blk & 7, idx = blk >> 3;
    const int bh = xcd * 8 + (idx & 7);
    const int pair = idx >> 3;                    // 0..7
    const int h = bh & 15, b = bh >> 4;

    const unsigned short* Kb = Kc + (size_t)bh * 73728;
    const unsigned short* Vb = Vt + (size_t)bh * 73728;
    const float* bias_b = biasT + b * 1152;

    const int srow = lane >> 3;                   // row within 8-row chunk
    const int scol = ((lane & 7) ^ srow) * 8;     // swizzled 16B block
    const int rswz = l16 & 7;                     // read-side swizzle key
    const int w16 = wave * 16;                    // this wave's staging rows

#define STAGE_KV(t0_, kdst_, vdst_)                                            \
    {                                                                          \
        const unsigned short* gk = Kb + (size_t)((t0_) + w16 + srow) * 64 + scol; \
        const unsigned short* gv = Vb + (size_t)(w16 + srow) * 1152 + (t0_) + scol; \
        _Pragma("unroll")                                                      \
        for (int cc = 0; cc < 2; cc++) {                                       \
            GLOAD_LDS16(gk + (size_t)(cc * 8) * 64,   &(kdst_)[(w16 + cc * 8) * 64]); \
            GLOAD_LDS16(gv + (size_t)(cc * 8) * 1152, &(vdst_)[(w16 + cc * 8) * 64]); \
        }                                                                      \
    }

    bf16x8 ones;
    #pragma unroll
    for (int j = 0; j < 8; j++) ones[j] = (short)0x3F80;  // bf16 1.0

    #pragma unroll
    for (int phase = 0; phase < 2; phase++) {
        const int qg = phase ? (15 - pair) : pair;  // uniform: (g+3)+(18-g)=21
        const int qrow0 = qg * 64;
        const int qrow_w = qrow0 + wave * 16;

        bf16x8 qf[2];
        #pragma unroll
        for (int k2 = 0; k2 < 2; k2++)
            qf[k2] = *(const bf16x8*)(Qbuf + (size_t)(b * 1024 + qrow_w + l16) * 1024 +
                                      h * 64 + k2 * 32 + quad * 8);

        f32x4 o[4] = {};
        f32x4 oden = {};
        const int tmax = min(1152, ((qrow0 + 255) >> 6) << 6);

        STAGE_KV(0, Ks[0], Vs[0]);  // prologue: stage tile 0

        for (int t0 = 0; t0 < tmax; t0 += 64) {
            const int cur = (t0 >> 6) & 1;
            if (t0 + 64 < tmax) {
                if (cur) { STAGE_KV(t0 + 64, Ks[0], Vs[0]); }
                else     { STAGE_KV(t0 + 64, Ks[1], Vs[1]); }
                asm volatile("s_waitcnt vmcnt(4)\n\ts_barrier" ::: "memory");
            } else {
                asm volatile("s_waitcnt vmcnt(0)\n\ts_barrier" ::: "memory");
            }
            if (t0 <= qrow_w + 143) {
                const unsigned short* Kcur = Ks[cur];
                const unsigned short* Vcur = Vs[cur];
                const bool nomask = (t0 + 63 <= 128 + qrow_w);
                float4 bt[4];
                #pragma unroll
                for (int tn = 0; tn < 4; tn++)
                    bt[tn] = *(const float4*)(bias_b + t0 + tn * 16 + quad * 4);
                const int sg = qrow_w + l16;
                #pragma unroll
                for (int tn = 0; tn < 4; tn++) {
                    bf16x8 kf0 = *(const bf16x8*)&Kcur[(tn * 16 + l16) * 64 + (quad ^ rswz) * 8];
                    bf16x8 kf1 = *(const bf16x8*)&Kcur[(tn * 16 + l16) * 64 + ((quad + 4) ^ rswz) * 8];
                    f32x4 st = {};
                    st = MFMA16(kf0, qf[0], st);
                    st = MFMA16(kf1, qf[1], st);
                    float p[4];
                    #pragma unroll
                    for (int r = 0; r < 4; r++) {
                        float e = __builtin_amdgcn_exp2f(st[r] * 0.18033688011112042f + bt[tn][r]);
                        if (!nomask) {
                            const int tg = t0 + tn * 16 + quad * 4 + r;
                            e = (tg < 128 || tg - 128 <= sg) ? e : 0.f;
                        }
                        p[r] = e;
                    }
                    union { ushort4 u; __hip_bfloat162 h2[2]; } pk;
                    pk.h2[0] = __float22bfloat162_rn(float2{p[0], p[1]});
                    pk.h2[1] = __float22bfloat162_rn(float2{p[2], p[3]});
                    *(ushort4*)&Ps[wave][l16 * 72 + tn * 16 + quad * 4] = pk.u;
                }
                #pragma unroll
                for (int tk = 0; tk < 2; tk++) {
                    bf16x8 pf = *(const bf16x8*)&Ps[wave][l16 * 72 + tk * 32 + quad * 8];
                    oden = MFMA16(pf, ones, oden);
                    #pragma unroll
                    for (int dn = 0; dn < 4; dn++) {
                        bf16x8 vf = *(const bf16x8*)&Vcur[(dn * 16 + l16) * 64 +
                                                          ((tk * 4 + quad) ^ rswz) * 8];
                        o[dn] = MFMA16(pf, vf, o[dn]);
                    }
                }
            }
            asm volatile("s_barrier" ::: "memory");
        }

        // epilogue: o C-layout row s = quad*4+r, col d = dn*16+l16
        #pragma unroll
        for (int r = 0; r < 4; r++) {
            const float inv = 1.f / oden[r];
            const size_t orow = (size_t)(b * 1024 + qrow_w + quad * 4 + r) * 1024 + h * 64;
            #pragma unroll
            for (int dn = 0; dn < 4; dn++)
                Aout[orow + dn * 16 + l16] = f2bf(o[dn][r] * inv);
        }
    }
#undef STAGE_KV
}

// ---------------------------------------------------------------------------
// proj (R7): 128x64 tiles, 512 blocks, BK=32 m97 staging, fp32 out.
__global__ __launch_bounds__(256) void gemm_proj(const unsigned short* __restrict__ Abuf,
                                                 const unsigned short* __restrict__ Wpt,
                                                 const float* __restrict__ b_proj,
                                                 float* __restrict__ out) {
    __shared__ unsigned short As[128 * 32];
    __shared__ unsigned short Bs[64 * 32];
    const int tid = threadIdx.x;
    const int lane = tid & 63, wave = tid >> 6;
    const int quad = lane >> 4, l16 = lane & 15;
    const int wm = (wave & 1) * 64, wn = (wave >> 1) * 32;
    const int bm = blockIdx.x & 31, bn = blockIdx.x >> 5;
    const int crow = lane >> 2, ccol = (lane & 3) * 8;
    const unsigned short* Abase = Abuf + (size_t)(bm * 128 + crow) * 1024 + ccol;
    const unsigned short* Bbase = Wpt + (size_t)(bn * 64 + crow) * 1024 + ccol;

    f32x4 acc[4][2] = {};
    for (int k0 = 0; k0 < 1024; k0 += 32) {
        __syncthreads();
        #pragma unroll
        for (int cc = 0; cc < 3; cc++) {
            const int c = wave * 3 + cc;
            if (c < 8) GLOAD_LDS16(Abase + (size_t)(c * 16) * 1024 + k0, &As[c * 512]);
            else if (c < 12) GLOAD_LDS16(Bbase + (size_t)((c - 8) * 16) * 1024 + k0, &Bs[(c - 8) * 512]);
        }
        __syncthreads();
        bf16x8 af[4], bf[2];
        #pragma unroll
        for (int i = 0; i < 4; i++) af[i] = *(const bf16x8*)&As[(wm + i * 16 + l16) * 32 + quad * 8];
        #pragma unroll
        for (int j = 0; j < 2; j++) bf[j] = *(const bf16x8*)&Bs[(wn + j * 16 + l16) * 32 + quad * 8];
        #pragma unroll
        for (int i = 0; i < 4; i++)
            #pragma unroll
            for (int j = 0; j < 2; j++)
                acc[i][j] = MFMA16(af[i], bf[j], acc[i][j]);
    }
    float bj[2];
    #pragma unroll
    for (int j = 0; j < 2; j++) bj[j] = b_proj[bn * 64 + wn + j * 16 + l16];
    #pragma unroll
    for (int i = 0; i < 4; i++) {
        const int row = bm * 128 + wm + i * 16 + quad * 4;
        #pragma unroll
        for (int j = 0; j < 2; j++) {
            const int col = bn * 64 + wn + j * 16 + l16;
            #pragma unroll
            for (int r = 0; r < 4; r++)
                out[(size_t)(row + r) * 1024 + col] = acc[i][j][r] + bj[j];
        }
    }
}

// ---------------------------------------------------------------------------
extern "C" void kernel_launch(void* const* d_in, const int* in_sizes, int n_in,
                              void* d_out, int out_size, void* d_ws, size_t ws_size,
                              hipStream_t stream) {
    const float* x      = (const float*)d_in[0];
    const float* Mem    = (const float*)d_in[1];
    const float* Mmask  = (const float*)d_in[2];
    const float* amask  = (const float*)d_in[3];
    const float* W_attn = (const float*)d_in[4];
    const float* b_attn = (const float*)d_in[5];
    const float* W_mem  = (const float*)d_in[6];
    const float* b_mem  = (const float*)d_in[7];
    const float* W_proj = (const float*)d_in[8];
    const float* b_proj = (const float*)d_in[9];
    float* out = (float*)d_out;

    char* ws = (char*)d_ws;
    unsigned short* x_bf  = (unsigned short*)ws;  ws += (size_t)4096 * 1024 * 2;
    unsigned short* M_bf  = (unsigned short*)ws;  ws += (size_t)512 * 1024 * 2;
    unsigned short* Wat   = (unsigned short*)ws;  ws += (size_t)3072 * 1024 * 2;
    unsigned short* Wmt   = (unsigned short*)ws;  ws += (size_t)2048 * 1024 * 2;
    unsigned short* Wpt   = (unsigned short*)ws;  ws += (size_t)1024 * 1024 * 2;
    unsigned short* Qbuf  = (unsigned short*)ws;  ws += (size_t)4096 * 1024 * 2;
    unsigned short* Abuf  = (unsigned short*)ws;  ws += (size_t)4096 * 1024 * 2;
    unsigned short* Kc    = (unsigned short*)ws;  ws += (size_t)64 * 1152 * 64 * 2;
    unsigned short* Vt    = (unsigned short*)ws;  ws += (size_t)64 * 64 * 1152 * 2;
    float*          biasT = (float*)ws;           ws += (size_t)4 * 1152 * 4;

    prep_all<<<6163, 256, 0, stream>>>(x, Mem, x_bf, M_bf, W_attn, W_mem, W_proj,
                                       Wat, Wmt, Wpt, Mmask, amask, biasT);
    gemm_fused<<<208, 512, 0, stream>>>(x_bf, Wat, b_attn, M_bf, Wmt, b_mem,
                                        Qbuf, Kc, Vt);
    attn_kernel<<<512, 256, 0, stream>>>(Qbuf, Kc, Vt, biasT, Abuf);
    gemm_proj<<<512, 256, 0, stream>>>(Abuf, Wpt, b_proj, out);
}

// Round 10
// 193.160 us; speedup vs baseline: 1.0316x; 1.0195x over previous
//
#include <hip/hip_runtime.h>
#include <hip/hip_bf16.h>

// ============================================================================
// ExtraAttention on MI355X (gfx950), bf16 MFMA pipeline.
// R19: proj upgraded — 128x128 tiles (was 128x64), 256 blocks (exactly 1/CU,
//      zero tail), 512 thr / 8 waves (wave-tile 64x32, acc[4][2] same as
//      before), BK=32 m97 staging. Halves A-panel refetch (8 col-tiles vs 16).
//      gemm_fused = R14 exact (fastest of 5 schedule variants, 42.3us —
//      schedule-invariant, stop touching). attn = R16 (QBLK=64, best total).
//      prep unchanged.
// Dims: B=4 S=1024 P=128 NX=1024 H=16 dh=64 T=1152
// ============================================================================

typedef __attribute__((ext_vector_type(8))) short bf16x8;
typedef __attribute__((ext_vector_type(4))) float f32x4;

#define MFMA16(a, b, c) __builtin_amdgcn_mfma_f32_16x16x32_bf16((a), (b), (c), 0, 0, 0)

#define GLOAD_LDS16(g, l)                                                  \
    __builtin_amdgcn_global_load_lds(                                      \
        (const __attribute__((address_space(1))) void*)(const void*)(g),   \
        (__attribute__((address_space(3))) void*)(void*)(l), 16, 0, 0)

static __device__ __forceinline__ unsigned short f2bf(float f) {
    union { float f; unsigned int u; } v; v.f = f;
    unsigned int u = v.u;
    return (unsigned short)((u + 0x7fffu + ((u >> 16) & 1u)) >> 16);  // RNE
}

// ---------------------------------------------------------------------------
// Fused prep: fp32->bf16 converts (x, M) + 3 weight transposes (64x64 tiles)
// + key-bias build.
static __device__ __forceinline__ void transpose64(const float* __restrict__ W,
                                                   unsigned short* __restrict__ Wt,
                                                   int K, int N, int bx, int by,
                                                   float* tile /* [64][65] */) {
    const int n0 = bx * 64, k0 = by * 64;
    const int tr = threadIdx.x >> 2, tc = (threadIdx.x & 3) * 16;
    #pragma unroll
    for (int i = 0; i < 4; i++) {
        float4 v = *(const float4*)&W[(size_t)(k0 + tr) * N + n0 + tc + i * 4];
        tile[tr * 65 + tc + i * 4 + 0] = v.x;
        tile[tr * 65 + tc + i * 4 + 1] = v.y;
        tile[tr * 65 + tc + i * 4 + 2] = v.z;
        tile[tr * 65 + tc + i * 4 + 3] = v.w;
    }
    __syncthreads();
    union { ushort4 u4[2]; unsigned short s[8]; } pk[2];
    #pragma unroll
    for (int half = 0; half < 2; half++)
        #pragma unroll
        for (int i = 0; i < 8; i++)
            pk[half].s[i] = f2bf(tile[(tc + half * 8 + i) * 65 + tr]);
    unsigned short* dst = &Wt[(size_t)(n0 + tr) * K + k0 + tc];
    *(ushort4*)(dst + 0) = pk[0].u4[0];
    *(ushort4*)(dst + 4) = pk[0].u4[1];
    *(ushort4*)(dst + 8) = pk[1].u4[0];
    *(ushort4*)(dst + 12) = pk[1].u4[1];
}

__global__ void prep_all(const float* __restrict__ x, const float* __restrict__ Mem,
                         unsigned short* __restrict__ x_bf, unsigned short* __restrict__ M_bf,
                         const float* __restrict__ W_attn, const float* __restrict__ W_mem,
                         const float* __restrict__ W_proj, unsigned short* __restrict__ Wat,
                         unsigned short* __restrict__ Wmt, unsigned short* __restrict__ Wpt,
                         const float* __restrict__ Mmask, const float* __restrict__ amask,
                         float* __restrict__ biasT) {
    __shared__ float tile[64 * 65];
    int bid = blockIdx.x;
    if (bid < 4608) {
        int i = bid * 256 + threadIdx.x;
        if (i < 1048576) {
            float4 v = ((const float4*)x)[i];
            ushort4 o; o.x = f2bf(v.x); o.y = f2bf(v.y); o.z = f2bf(v.z); o.w = f2bf(v.w);
            ((ushort4*)x_bf)[i] = o;
        } else {
            int j = i - 1048576;
            float4 v = ((const float4*)Mem)[j];
            ushort4 o; o.x = f2bf(v.x); o.y = f2bf(v.y); o.z = f2bf(v.z); o.w = f2bf(v.w);
            ((ushort4*)M_bf)[j] = o;
        }
        return;
    }
    bid -= 4608;
    if (bid < 768) {
        transpose64(W_attn, Wat, 1024, 3072, bid % 48, bid / 48, tile);
    } else if (bid < 1280) {
        int t = bid - 768;  transpose64(W_mem, Wmt, 1024, 2048, t % 32, t / 32, tile);
    } else if (bid < 1536) {
        int t = bid - 1280; transpose64(W_proj, Wpt, 1024, 1024, t % 16, t / 16, tile);
    } else {
        int i = (bid - 1536) * 256 + threadIdx.x;
        if (i < 4 * 1152) {
            int b = i / 1152, t = i % 1152;
            float v = (t < 128) ? (Mmask[b * 128 + t] - 1.f) * 10000.f
                                : amask[b * 1024 + t - 128];
            biasT[i] = v * 1.4426950408889634f;
        }
    }
}

// ---------------------------------------------------------------------------
// R14 gemm_fused: 256x256 tile, BK=64, 512 thr (8 waves 2Mx4N), 128KB dbuf
// XOR-swizzled LDS, 4-phase/K-tile schedule.
// bid<192: QKV (A=x_bf[4096][1024], Bt=Wat[3072][1024], 16x12 tiles, XCD remap)
// else   : EKV (A=M_bf[512][1024],  Bt=Wmt[2048][1024], 2x8 tiles)
__global__ __launch_bounds__(512, 2) void gemm_fused(
        const unsigned short* __restrict__ x_bf, const unsigned short* __restrict__ Wat,
        const float* __restrict__ b_attn, const unsigned short* __restrict__ M_bf,
        const unsigned short* __restrict__ Wmt, const float* __restrict__ b_mem,
        unsigned short* __restrict__ Qbuf, unsigned short* __restrict__ Kc,
        unsigned short* __restrict__ Vt) {
    __shared__ unsigned short lds[2][32768];  // [slot][A 16K elems | B 16K elems]
    const int tid = threadIdx.x;
    const int lane = tid & 63, wave = tid >> 6;
    const int quad = lane >> 4, l16 = lane & 15;
    const int l7 = l16 & 7;
    const int srow = lane >> 3;                 // staging: row within 8-row chunk
    const int sblk = (lane & 7) ^ srow;         // staging: pre-swizzled src block
    const int wrow = wave * 16;                 // staging: wave's rows in a half
    const int wm = (wave & 1) * 128;            // wave output rows (M)
    const int wn = (wave >> 1) * 64;            // wave output cols (N)

    int tm, tn;
    const unsigned short *Ab, *Bb;
    const float* bias;
    bool qkv;
    if (blockIdx.x < 192) {
        const int nb = (blockIdx.x & 7) * 24 + (blockIdx.x >> 3);  // XCD-contig
        tm = nb & 15; tn = nb >> 4;            // 16 x 12
        Ab = x_bf; Bb = Wat; bias = b_attn; qkv = true;
    } else {
        const int e = blockIdx.x - 192;
        tm = e >> 3; tn = e & 7;               // 2 x 8
        Ab = M_bf; Bb = Wmt; bias = b_mem; qkv = false;
    }
    const int Mrow0 = tm * 256, Nrow0 = tn * 256;

    // stage one 128-row half (2 x gload_lds per thread) of K-tile kt1 into slot
#define STG(slot, dstoff, srcp, row0, kt1)                                     \
    { _Pragma("unroll")                                                        \
      for (int c = 0; c < 2; c++)                                              \
          GLOAD_LDS16((srcp) + (size_t)((row0) + wrow + c * 8 + srow) * 1024 + \
                          (kt1) * 64 + sblk * 8,                               \
                      &lds[slot][(dstoff) + (wrow + c * 8) * 64]); }

    // prologue: stage K-tile 0 fully into slot 0
    STG(0, 16384, Bb, Nrow0, 0); STG(0, 24576, Bb, Nrow0 + 128, 0);
    STG(0, 0,     Ab, Mrow0, 0); STG(0, 8192,  Ab, Mrow0 + 128, 0);
    asm volatile("s_waitcnt vmcnt(0)\n\ts_barrier" ::: "memory");

    f32x4 acc[8][4] = {};
    for (int kt = 0; kt < 16; kt++) {
        const int s = kt & 1, nx = s ^ 1;
        bf16x8 bfr[4][2];
        #pragma unroll
        for (int p = 0; p < 4; p++) {
            bf16x8 af[2][2];
            #pragma unroll
            for (int k = 0; k < 2; k++)
                #pragma unroll
                for (int ks = 0; ks < 2; ks++)
                    af[k][ks] = *(const bf16x8*)&lds[s][(wm + (2 * p + k) * 16 + l16) * 64 +
                                                       (((ks * 4 + quad) ^ l7) * 8)];
            if (p == 0) {
                #pragma unroll
                for (int j = 0; j < 4; j++)
                    #pragma unroll
                    for (int ks = 0; ks < 2; ks++)
                        bfr[j][ks] = *(const bf16x8*)&lds[s][16384 + (wn + j * 16 + l16) * 64 +
                                                            (((ks * 4 + quad) ^ l7) * 8)];
            }
            if (kt < 15) {  // stage kt+1 into slot nx (fully freed last K-tile)
                if (p == 0) { STG(nx, 16384, Bb, Nrow0, kt + 1);
                              STG(nx, 24576, Bb, Nrow0 + 128, kt + 1); }
                else if (p == 1) { STG(nx, 0,    Ab, Mrow0, kt + 1); }
                else if (p == 2) { STG(nx, 8192, Ab, Mrow0 + 128, kt + 1); }
            }
            if (p == 3) asm volatile("s_waitcnt vmcnt(0)\n\ts_barrier" ::: "memory");
            else        asm volatile("s_barrier" ::: "memory");
            __builtin_amdgcn_s_setprio(1);
            #pragma unroll
            for (int k = 0; k < 2; k++)
                #pragma unroll
                for (int j = 0; j < 4; j++) {
                    acc[2 * p + k][j] = MFMA16(af[k][0], bfr[j][0], acc[2 * p + k][j]);
                    acc[2 * p + k][j] = MFMA16(af[k][1], bfr[j][1], acc[2 * p + k][j]);
                }
            __builtin_amdgcn_s_setprio(0);
            asm volatile("s_barrier" ::: "memory");
        }
    }
#undef STG
    __syncthreads();  // main loop fully done; LDS reusable for transposes

    float bj[4];
    #pragma unroll
    for (int j = 0; j < 4; j++) bj[j] = bias[Nrow0 + wn + j * 16 + l16];

    if (qkv) {
        const int b = tm >> 2;
        const int sb = (tm & 3) * 256 + wm;    // row within [0,1024)
        if (tn < 4) {
            // ---- q -> Qbuf[4096][1024]
            #pragma unroll
            for (int i = 0; i < 8; i++) {
                const int row = Mrow0 + wm + i * 16 + quad * 4;
                #pragma unroll
                for (int j = 0; j < 4; j++) {
                    const int col = Nrow0 + wn + j * 16 + l16;
                    #pragma unroll
                    for (int r = 0; r < 4; r++)
                        Qbuf[(size_t)(row + r) * 1024 + col] = f2bf(acc[i][j][r] + bj[j]);
                }
            }
        } else if (tn < 8) {
            // ---- k -> Kc[bh][t=s+128][d]
            const int cb = (tn - 4) * 256 + wn;
            unsigned short* kb2 = Kc + (size_t)((b << 4) | (cb >> 6)) * 73728;
            #pragma unroll
            for (int i = 0; i < 8; i++) {
                const int s0 = sb + i * 16 + quad * 4;
                #pragma unroll
                for (int j = 0; j < 4; j++) {
                    const int d = j * 16 + l16;
                    #pragma unroll
                    for (int r = 0; r < 4; r++)
                        kb2[(size_t)(128 + s0 + r) * 64 + d] = f2bf(acc[i][j][r] + bj[j]);
                }
            }
        } else {
            // ---- v -> Vt[bh][d][t] via per-wave LDS transpose (64x64, stride 68)
            const int vb = (tn - 8) * 256 + wn;
            unsigned short* Tw = &lds[0][0] + wave * 4352;
            unsigned short* vdb = Vt + (size_t)((b << 4) | (vb >> 6)) * 73728;
            #pragma unroll
            for (int hf = 0; hf < 2; hf++) {
                #pragma unroll
                for (int i2 = 0; i2 < 4; i2++)
                    #pragma unroll
                    for (int j = 0; j < 4; j++)
                        #pragma unroll
                        for (int r = 0; r < 4; r++)
                            Tw[(j * 16 + l16) * 68 + i2 * 16 + quad * 4 + r] =
                                f2bf(acc[hf * 4 + i2][j][r] + bj[j]);
                unsigned short* vd = vdb + (size_t)lane * 1152 + 128 + sb + hf * 64;
                #pragma unroll
                for (int ch = 0; ch < 8; ch++)
                    *(bf16x8*)(vd + ch * 8) = *(const bf16x8*)&Tw[lane * 68 + ch * 8];
            }
        }
    } else {
        const int b = (Mrow0 + wm) >> 7;
        if (tn < 4) {
            // ---- ek -> Kc[bh][t=p][d]
            const int cb = tn * 256 + wn;
            unsigned short* kb2 = Kc + (size_t)((b << 4) | (cb >> 6)) * 73728;
            #pragma unroll
            for (int i = 0; i < 8; i++) {
                const int p0 = i * 16 + quad * 4;
                #pragma unroll
                for (int j = 0; j < 4; j++) {
                    const int d = j * 16 + l16;
                    #pragma unroll
                    for (int r = 0; r < 4; r++)
                        kb2[(size_t)(p0 + r) * 64 + d] = f2bf(acc[i][j][r] + bj[j]);
                }
            }
        } else {
            // ---- ev -> Vt[bh][d][p] via per-wave LDS transpose
            const int vb = (tn - 4) * 256 + wn;
            unsigned short* Tw = &lds[0][0] + wave * 4352;
            unsigned short* vdb = Vt + (size_t)((b << 4) | (vb >> 6)) * 73728;
            #pragma unroll
            for (int hf = 0; hf < 2; hf++) {
                #pragma unroll
                for (int i2 = 0; i2 < 4; i2++)
                    #pragma unroll
                    for (int j = 0; j < 4; j++)
                        #pragma unroll
                        for (int r = 0; r < 4; r++)
                            Tw[(j * 16 + l16) * 68 + i2 * 16 + quad * 4 + r] =
                                f2bf(acc[hf * 4 + i2][j][r] + bj[j]);
                unsigned short* vd = vdb + (size_t)lane * 1152 + hf * 64;
                #pragma unroll
                for (int ch = 0; ch < 8; ch++)
                    *(bf16x8*)(vd + ch * 8) = *(const bf16x8*)&Tw[lane * 68 + ch * 8];
            }
        }
    }
}

// ---------------------------------------------------------------------------
// Attention (R16, best-total config): QBLK=64 — 512 blocks x 256 thr
// (4 waves), dbuf K/V, counted vmcnt(4), uniform pairing (21 iters/block).
__global__ __launch_bounds__(256) void attn_kernel(const unsigned short* __restrict__ Qbuf,
                                                   const unsigned short* __restrict__ Kc,
                                                   const unsigned short* __restrict__ Vt,
                                                   const float* __restrict__ biasT,
                                                   unsigned short* __restrict__ Aout) {
    __shared__ unsigned short Ks[2][64 * 64];
    __shared__ unsigned short Vs[2][64 * 64];
    __shared__ unsigned short Ps[4][16 * 72];
    const int tid = threadIdx.x;
    const int lane = tid & 63, wave = tid >> 6;   // wave 0..3
    const int quad = lane >> 4, l16 = lane & 15;
    const int blk = blockIdx.x;                   // 512 = 8 xcd x 8 bh x 8 pair
    const int xcd = blk & 7, idx = blk >> 3;
    const int bh = xcd * 8 + (idx & 7);
    const int pair = idx >> 3;                    // 0..7
    const int h = bh & 15, b = bh >> 4;

    const unsigned short* Kb = Kc + (size_t)bh * 73728;
    const unsigned short* Vb = Vt + (size_t)bh * 73728;
    const float* bias_b = biasT + b * 1152;

    const int srow = lane >> 3;                   // row within 8-row chunk
    const int scol = ((lane & 7) ^ srow) * 8;     // swizzled 16B block
    const int rswz = l16 & 7;                     // read-side swizzle key
    const int w16 = wave * 16;                    // this wave's staging rows

#define STAGE_KV(t0_, kdst_, vdst_)                                            \
    {                                                                          \
        const unsigned short* gk = Kb + (size_t)((t0_) + w16 + srow) * 64 + scol; \
        const unsigned short* gv = Vb + (size_t)(w16 + srow) * 1152 + (t0_) + scol; \
        _Pragma("unroll")                                                      \
        for (int cc = 0; cc < 2; cc++) {                                       \
            GLOAD_LDS16(gk + (size_t)(cc * 8) * 64,   &(kdst_)[(w16 + cc * 8) * 64]); \
            GLOAD_LDS16(gv + (size_t)(cc * 8) * 1152, &(vdst_)[(w16 + cc * 8) * 64]); \
        }                                                                      \
    }

    bf16x8 ones;
    #pragma unroll
    for (int j = 0; j < 8; j++) ones[j] = (short)0x3F80;  // bf16 1.0

    #pragma unroll
    for (int phase = 0; phase < 2; phase++) {
        const int qg = phase ? (15 - pair) : pair;  // uniform: (g+3)+(18-g)=21
        const int qrow0 = qg * 64;
        const int qrow_w = qrow0 + wave * 16;

        bf16x8 qf[2];
        #pragma unroll
        for (int k2 = 0; k2 < 2; k2++)
            qf[k2] = *(const bf16x8*)(Qbuf + (size_t)(b * 1024 + qrow_w + l16) * 1024 +
                                      h * 64 + k2 * 32 + quad * 8);

        f32x4 o[4] = {};
        f32x4 oden = {};
        const int tmax = min(1152, ((qrow0 + 255) >> 6) << 6);

        STAGE_KV(0, Ks[0], Vs[0]);  // prologue: stage tile 0

        for (int t0 = 0; t0 < tmax; t0 += 64) {
            const int cur = (t0 >> 6) & 1;
            if (t0 + 64 < tmax) {
                if (cur) { STAGE_KV(t0 + 64, Ks[0], Vs[0]); }
                else     { STAGE_KV(t0 + 64, Ks[1], Vs[1]); }
                asm volatile("s_waitcnt vmcnt(4)\n\ts_barrier" ::: "memory");
            } else {
                asm volatile("s_waitcnt vmcnt(0)\n\ts_barrier" ::: "memory");
            }
            if (t0 <= qrow_w + 143) {
                const unsigned short* Kcur = Ks[cur];
                const unsigned short* Vcur = Vs[cur];
                const bool nomask = (t0 + 63 <= 128 + qrow_w);
                float4 bt[4];
                #pragma unroll
                for (int tn = 0; tn < 4; tn++)
                    bt[tn] = *(const float4*)(bias_b + t0 + tn * 16 + quad * 4);
                const int sg = qrow_w + l16;
                #pragma unroll
                for (int tn = 0; tn < 4; tn++) {
                    bf16x8 kf0 = *(const bf16x8*)&Kcur[(tn * 16 + l16) * 64 + (quad ^ rswz) * 8];
                    bf16x8 kf1 = *(const bf16x8*)&Kcur[(tn * 16 + l16) * 64 + ((quad + 4) ^ rswz) * 8];
                    f32x4 st = {};
                    st = MFMA16(kf0, qf[0], st);
                    st = MFMA16(kf1, qf[1], st);
                    float p[4];
                    #pragma unroll
                    for (int r = 0; r < 4; r++) {
                        float e = __builtin_amdgcn_exp2f(st[r] * 0.18033688011112042f + bt[tn][r]);
                        if (!nomask) {
                            const int tg = t0 + tn * 16 + quad * 4 + r;
                            e = (tg < 128 || tg - 128 <= sg) ? e : 0.f;
                        }
                        p[r] = e;
                    }
                    union { ushort4 u; __hip_bfloat162 h2[2]; } pk;
                    pk.h2[0] = __float22bfloat162_rn(float2{p[0], p[1]});
                    pk.h2[1] = __float22bfloat162_rn(float2{p[2], p[3]});
                    *(ushort4*)&Ps[wave][l16 * 72 + tn * 16 + quad * 4] = pk.u;
                }
                #pragma unroll
                for (int tk = 0; tk < 2; tk++) {
                    bf16x8 pf = *(const bf16x8*)&Ps[wave][l16 * 72 + tk * 32 + quad * 8];
                    oden = MFMA16(pf, ones, oden);
                    #pragma unroll
                    for (int dn = 0; dn < 4; dn++) {
                        bf16x8 vf = *(const bf16x8*)&Vcur[(dn * 16 + l16) * 64 +
                                                          ((tk * 4 + quad) ^ rswz) * 8];
                        o[dn] = MFMA16(pf, vf, o[dn]);
                    }
                }
            }
            asm volatile("s_barrier" ::: "memory");
        }

        // epilogue: o C-layout row s = quad*4+r, col d = dn*16+l16
        #pragma unroll
        for (int r = 0; r < 4; r++) {
            const float inv = 1.f / oden[r];
            const size_t orow = (size_t)(b * 1024 + qrow_w + quad * 4 + r) * 1024 + h * 64;
            #pragma unroll
            for (int dn = 0; dn < 4; dn++)
                Aout[orow + dn * 16 + l16] = f2bf(o[dn][r] * inv);
        }
    }
#undef STAGE_KV
}

// ---------------------------------------------------------------------------
// proj (R19): 128x128 tiles, 256 blocks (1/CU exact), 512 thr (8 waves,
// wave-tile 64x32, acc[4][2]), BK=32 m97 staging. Halves A-panel refetch.
__global__ __launch_bounds__(512) void gemm_proj(const unsigned short* __restrict__ Abuf,
                                                 const unsigned short* __restrict__ Wpt,
                                                 const float* __restrict__ b_proj,
                                                 float* __restrict__ out) {
    __shared__ unsigned short As[128 * 32];
    __shared__ unsigned short Bs[128 * 32];
    const int tid = threadIdx.x;
    const int lane = tid & 63, wave = tid >> 6;   // 0..7
    const int quad = lane >> 4, l16 = lane & 15;
    const int wm = (wave & 1) * 64, wn = (wave >> 1) * 32;  // 2M x 4N = 128x128
    const int bm = blockIdx.x & 31, bn = blockIdx.x >> 5;   // 32 x 8
    const int crow = lane >> 2, ccol = (lane & 3) * 8;
    const unsigned short* Abase = Abuf + (size_t)(bm * 128 + crow) * 1024 + ccol;
    const unsigned short* Bbase = Wpt + (size_t)(bn * 128 + crow) * 1024 + ccol;

    f32x4 acc[4][2] = {};
    for (int k0 = 0; k0 < 1024; k0 += 32) {
        __syncthreads();
        #pragma unroll
        for (int cc = 0; cc < 2; cc++) {
            const int c = wave * 2 + cc;          // 0..15
            if (c < 8) GLOAD_LDS16(Abase + (size_t)(c * 16) * 1024 + k0, &As[c * 512]);
            else       GLOAD_LDS16(Bbase + (size_t)((c - 8) * 16) * 1024 + k0, &Bs[(c - 8) * 512]);
        }
        __syncthreads();
        bf16x8 af[4], bf[2];
        #pragma unroll
        for (int i = 0; i < 4; i++) af[i] = *(const bf16x8*)&As[(wm + i * 16 + l16) * 32 + quad * 8];
        #pragma unroll
        for (int j = 0; j < 2; j++) bf[j] = *(const bf16x8*)&Bs[(wn + j * 16 + l16) * 32 + quad * 8];
        #pragma unroll
        for (int i = 0; i < 4; i++)
            #pragma unroll
            for (int j = 0; j < 2; j++)
                acc[i][j] = MFMA16(af[i], bf[j], acc[i][j]);
    }
    float bj[2];
    #pragma unroll
    for (int j = 0; j < 2; j++) bj[j] = b_proj[bn * 128 + wn + j * 16 + l16];
    #pragma unroll
    for (int i = 0; i < 4; i++) {
        const int row = bm * 128 + wm + i * 16 + quad * 4;
        #pragma unroll
        for (int j = 0; j < 2; j++) {
            const int col = bn * 128 + wn + j * 16 + l16;
            #pragma unroll
            for (int r = 0; r < 4; r++)
                out[(size_t)(row + r) * 1024 + col] = acc[i][j][r] + bj[j];
        }
    }
}

// ---------------------------------------------------------------------------
extern "C" void kernel_launch(void* const* d_in, const int* in_sizes, int n_in,
                              void* d_out, int out_size, void* d_ws, size_t ws_size,
                              hipStream_t stream) {
    const float* x      = (const float*)d_in[0];
    const float* Mem    = (const float*)d_in[1];
    const float* Mmask  = (const float*)d_in[2];
    const float* amask  = (const float*)d_in[3];
    const float* W_attn = (const float*)d_in[4];
    const float* b_attn = (const float*)d_in[5];
    const float* W_mem  = (const float*)d_in[6];
    const float* b_mem  = (const float*)d_in[7];
    const float* W_proj = (const float*)d_in[8];
    const float* b_proj = (const float*)d_in[9];
    float* out = (float*)d_out;

    char* ws = (char*)d_ws;
    unsigned short* x_bf  = (unsigned short*)ws;  ws += (size_t)4096 * 1024 * 2;
    unsigned short* M_bf  = (unsigned short*)ws;  ws += (size_t)512 * 1024 * 2;
    unsigned short* Wat   = (unsigned short*)ws;  ws += (size_t)3072 * 1024 * 2;
    unsigned short* Wmt   = (unsigned short*)ws;  ws += (size_t)2048 * 1024 * 2;
    unsigned short* Wpt   = (unsigned short*)ws;  ws += (size_t)1024 * 1024 * 2;
    unsigned short* Qbuf  = (unsigned short*)ws;  ws += (size_t)4096 * 1024 * 2;
    unsigned short* Abuf  = (unsigned short*)ws;  ws += (size_t)4096 * 1024 * 2;
    unsigned short* Kc    = (unsigned short*)ws;  ws += (size_t)64 * 1152 * 64 * 2;
    unsigned short* Vt    = (unsigned short*)ws;  ws += (size_t)64 * 64 * 1152 * 2;
    float*          biasT = (float*)ws;           ws += (size_t)4 * 1152 * 4;

    prep_all<<<6163, 256, 0, stream>>>(x, Mem, x_bf, M_bf, W_attn, W_mem, W_proj,
                                       Wat, Wmt, Wpt, Mmask, amask, biasT);
    gemm_fused<<<208, 512, 0, stream>>>(x_bf, Wat, b_attn, M_bf, Wmt, b_mem,
                                        Qbuf, Kc, Vt);
    attn_kernel<<<512, 256, 0, stream>>>(Qbuf, Kc, Vt, biasT, Abuf);
    gemm_proj<<<256, 512, 0, stream>>>(Abuf, Wpt, b_proj, out);
}